// Round 4
// baseline (598.720 us; speedup 1.0000x reference)
//
#include <hip/hip_runtime.h>
#include <cstdint>
#include <cstddef>

typedef short short8 __attribute__((ext_vector_type(8)));
typedef short s16x4 __attribute__((ext_vector_type(4)));
typedef float f32x4 __attribute__((ext_vector_type(4)));

typedef const __attribute__((address_space(1))) void* gas_ptr;
typedef __attribute__((address_space(3))) void* las_ptr;

__device__ __forceinline__ unsigned short f2bf(float f) {
    unsigned int u = __float_as_uint(f);
    u += 0x7fffu + ((u >> 16) & 1u);          // RNE (finite inputs)
    return (unsigned short)(u >> 16);
}
__device__ __forceinline__ float bf2f(unsigned short s) {
    return __uint_as_float(((unsigned int)s) << 16);
}
__device__ __forceinline__ float sigmoid_f(float z) {
    return __builtin_amdgcn_rcpf(1.0f + __expf(-z));
}
__device__ __forceinline__ void async_copy16(const void* gp, void* lp) {
    __builtin_amdgcn_global_load_lds((gas_ptr)gp, (las_ptr)lp, 16, 0, 0);
}

// ---------------- converters ----------------
// x: [32768,1024] f32 -> bf16, same layout. 8 elems/thread.
__global__ __launch_bounds__(256) void cvt_x_kernel(const float* __restrict__ in,
                                                    unsigned short* __restrict__ out) {
    size_t i = ((size_t)blockIdx.x * 256 + threadIdx.x) * 8;
    float4 v0 = *(const float4*)(in + i);
    float4 v1 = *(const float4*)(in + i + 4);
    short8 o;
    o[0]=(short)f2bf(v0.x); o[1]=(short)f2bf(v0.y); o[2]=(short)f2bf(v0.z); o[3]=(short)f2bf(v0.w);
    o[4]=(short)f2bf(v1.x); o[5]=(short)f2bf(v1.y); o[6]=(short)f2bf(v1.z); o[7]=(short)f2bf(v1.w);
    *(short8*)(out + i) = o;
}

// W: [1024,4096] f32 -> W_T bf16 [4096,1024]. 64x64 LDS tiles.
__global__ __launch_bounds__(256) void cvt_w_kernel(const float* __restrict__ W,
                                                    unsigned short* __restrict__ Wt) {
    __shared__ unsigned short tile[64][65];
    int bk = blockIdx.x >> 6, bn = blockIdx.x & 63;
    int k0 = bk * 64, n0 = bn * 64;
    int t = threadIdx.x;
    int cr = t >> 6;          // 0..3
    int cc = t & 63;          // 0..63
#pragma unroll
    for (int i = 0; i < 16; ++i) {
        int row = i * 4 + cr;
        tile[row][cc] = f2bf(W[(size_t)(k0 + row) * 4096 + n0 + cc]);
    }
    __syncthreads();
#pragma unroll
    for (int i = 0; i < 16; ++i) {
        int nrow = i * 4 + cr;
        Wt[(size_t)(n0 + nrow) * 1024 + k0 + cc] = tile[cc][nrow];
    }
}

// ---------------- GEMM ----------------
// C[m][n] = sum_k A[m][k]*B_T[n][k], m=b*1024+t (M=32768), n=gate*1024+u (N=4096), K=1024.
// Output layout (scan-optimized): gT[gate][b][u>>6][t>>3][u&63][t&7] bf16 —
// a scan-wave's 64 lanes read one 8-timestep chunk as ONE contiguous 1 KB span.
// 128x128 tile, BK=64, 4 waves in 2x2, each wave 4x4 frags of 16x16x32 bf16 MFMA.
__global__ __launch_bounds__(256, 2) void gemm_kernel(const unsigned short* __restrict__ A,
                                                      const unsigned short* __restrict__ Bt,
                                                      const float* __restrict__ bias,
                                                      unsigned short* __restrict__ gT) {
    __shared__ __align__(16) unsigned short As[128 * 64];
    __shared__ __align__(16) unsigned short Bs[128 * 64];

    // band swizzle: 8 m-tiles x 32 n-tiles per band, n fastest
    int bid = blockIdx.x;
    int band = bid >> 8;
    int r = bid & 255;
    int mt = band * 8 + (r >> 5);
    int nt = r & 31;
    int m0 = mt * 128, n0 = nt * 128;

    int tidx = threadIdx.x;
    int lane = tidx & 63, wv = tidx >> 6;
    int wm = wv >> 1, wn = wv & 1;
    int l15 = lane & 15, quad = lane >> 4;

    f32x4 acc[4][4] = {};

    for (int k0 = 0; k0 < 1024; k0 += 64) {
        __syncthreads();
#pragma unroll
        for (int i = 0; i < 4; ++i) {
            int ci = (wv * 4 + i) * 64 + lane;      // 0..1023
            int row = ci >> 3, cc = ci & 7;
            int sc = (cc ^ (row & 7)) << 3;         // swizzled k-offset (elements)
            const unsigned short* ga = A + (size_t)(m0 + row) * 1024 + k0 + sc;
            async_copy16(ga, (char*)As + (wv * 4 + i) * 1024);
            const unsigned short* gb = Bt + (size_t)(n0 + row) * 1024 + k0 + sc;
            async_copy16(gb, (char*)Bs + (wv * 4 + i) * 1024);
        }
        __syncthreads();
#pragma unroll
        for (int kt = 0; kt < 2; ++kt) {
            short8 af[4], bf[4];
#pragma unroll
            for (int mt2 = 0; mt2 < 4; ++mt2) {
                int row = wm * 64 + mt2 * 16 + l15;
                int kc = kt * 4 + quad;
                af[mt2] = *(const short8*)((const char*)As + row * 128 + ((kc ^ (row & 7)) << 4));
            }
#pragma unroll
            for (int nt2 = 0; nt2 < 4; ++nt2) {
                int rown = wn * 64 + nt2 * 16 + l15;
                int kc = kt * 4 + quad;
                bf[nt2] = *(const short8*)((const char*)Bs + rown * 128 + ((kc ^ (rown & 7)) << 4));
            }
#pragma unroll
            for (int mt2 = 0; mt2 < 4; ++mt2)
#pragma unroll
                for (int nt2 = 0; nt2 < 4; ++nt2)
                    acc[mt2][nt2] = __builtin_amdgcn_mfma_f32_16x16x32_bf16(
                        af[mt2], bf[nt2], acc[mt2][nt2], 0, 0, 0);
        }
    }

    // epilogue: C/D layout col=lane&15, row=quad*4+reg.
    // rr=0..3 are consecutive m => consecutive t => one 8-B store into the
    // interleaved layout (t&7 in {0,4}, never crosses an 8-t chunk).
#pragma unroll
    for (int mt2 = 0; mt2 < 4; ++mt2) {
        int mbase = m0 + wm * 64 + mt2 * 16 + quad * 4;
        int b_ = mbase >> 10, t_ = mbase & 1023;
        int tc = t_ >> 3, tt = t_ & 7;
#pragma unroll
        for (int nt2 = 0; nt2 < 4; ++nt2) {
            int n = n0 + wn * 64 + nt2 * 16 + l15;
            int gate = n >> 10, u = n & 1023;
            int ug = u >> 6, ul = u & 63;
            float bv = bias[n];
            s16x4 pk;
            pk[0] = (short)f2bf(acc[mt2][nt2][0] + bv);
            pk[1] = (short)f2bf(acc[mt2][nt2][1] + bv);
            pk[2] = (short)f2bf(acc[mt2][nt2][2] + bv);
            pk[3] = (short)f2bf(acc[mt2][nt2][3] + bv);
            size_t addr = ((((size_t)(gate * 32 + b_) * 16 + ug) * 128 + tc) * 512)
                          + (size_t)(ul * 8 + tt);
            *(s16x4*)(gT + addr) = pk;
        }
    }
}

// ---------------- sequential scan ----------------
// thread = one (b,u). gT bf16 [4][B][16][128][64][8]; h f32 [B,T,U].
// 8-deep branch-free register ring: 32 outstanding 1-KB contiguous wave-loads.
__global__ __launch_bounds__(64) void scan_kernel(const unsigned short* __restrict__ gT,
                                                  const float* __restrict__ c0,
                                                  const float* __restrict__ Vr,
                                                  const float* __restrict__ Vf,
                                                  float* __restrict__ h) {
    int ul = threadIdx.x;                        // 0..63 == u & 63
    int tid = blockIdx.x * 64 + ul;              // 0..32767
    int b = tid >> 10, u = tid & 1023;
    int ug = u >> 6;
    const size_t PLANE = (size_t)33554432;       // gate stride: 32*16*128*512
    const unsigned short* p1 = gT + (((size_t)b * 16 + ug) * 128) * 512 + (size_t)(ul * 8);
    const unsigned short* p2 = p1 + PLANE;
    const unsigned short* p3 = p2 + PLANE;
    const unsigned short* p4 = p3 + PLANE;
    float* hb = h + ((size_t)b << 20) + u;
    float c = c0[(b << 10) + u];
    float vf = Vf[u], vr = Vr[u];

    short8 r1[8], r2[8], r3[8], r4[8];
#pragma unroll
    for (int j = 0; j < 8; ++j) {
        r1[j] = *(const short8*)(p1 + (size_t)j * 512);
        r2[j] = *(const short8*)(p2 + (size_t)j * 512);
        r3[j] = *(const short8*)(p3 + (size_t)j * 512);
        r4[j] = *(const short8*)(p4 + (size_t)j * 512);
    }

#define SRU_CHUNK(TC, PREFETCH)                                                \
    {                                                                          \
        int s_ = (TC) & 7;                                                     \
        short8 a1 = r1[s_], a2 = r2[s_], a3 = r3[s_], a4 = r4[s_];             \
        if (PREFETCH) {                                                        \
            size_t off_ = (size_t)((TC) + 8) * 512;                            \
            r1[s_] = *(const short8*)(p1 + off_);                              \
            r2[s_] = *(const short8*)(p2 + off_);                              \
            r3[s_] = *(const short8*)(p3 + off_);                              \
            r4[s_] = *(const short8*)(p4 + off_);                              \
        }                                                                      \
        int t0_ = (TC) * 8;                                                    \
        _Pragma("unroll")                                                      \
        for (int i = 0; i < 8; ++i) {                                          \
            float x1 = bf2f((unsigned short)a1[i]);                            \
            float x2 = bf2f((unsigned short)a2[i]);                            \
            float x3 = bf2f((unsigned short)a3[i]);                            \
            float x4 = bf2f((unsigned short)a4[i]);                            \
            float f  = sigmoid_f(x1 + vf * c);                                 \
            float cn = fmaf(f, c - x2, x2);                                    \
            float rr = sigmoid_f(x3 + vr * c);                                 \
            float hv = fmaf(rr, cn - x4, x4);                                  \
            c = cn;                                                            \
            __builtin_nontemporal_store(hv, &hb[(size_t)(t0_ + i) << 10]);     \
        }                                                                      \
    }

#pragma unroll 8
    for (int tc = 0; tc < 120; ++tc) SRU_CHUNK(tc, 1)
#pragma unroll
    for (int tc = 120; tc < 128; ++tc) SRU_CHUNK(tc, 0)
#undef SRU_CHUNK
}

extern "C" void kernel_launch(void* const* d_in, const int* in_sizes, int n_in,
                              void* d_out, int out_size, void* d_ws, size_t ws_size,
                              hipStream_t stream) {
    const float* x  = (const float*)d_in[0];
    // d_in[1] = h0 (unused by reference)
    const float* c0 = (const float*)d_in[2];
    const float* W  = (const float*)d_in[3];
    const float* b  = (const float*)d_in[4];
    const float* Vr = (const float*)d_in[5];
    const float* Vf = (const float*)d_in[6];
    float* h = (float*)d_out;

    char* ws = (char*)d_ws;
    unsigned short* xb = (unsigned short*)ws;                         // 64 MB
    unsigned short* wt = (unsigned short*)(ws + (size_t)67108864);    // 8 MB
    unsigned short* gT = (unsigned short*)(ws + (size_t)75497472);    // 256 MB

    cvt_x_kernel<<<16384, 256, 0, stream>>>(x, xb);
    cvt_w_kernel<<<1024, 256, 0, stream>>>(W, wt);
    gemm_kernel<<<8192, 256, 0, stream>>>(xb, wt, b, gT);
    scan_kernel<<<512, 64, 0, stream>>>(gT, c0, Vr, Vf, h);
}